// Round 2
// baseline (126.911 us; speedup 1.0000x reference)
//
#include <hip/hip_runtime.h>
#include <hip/hip_bf16.h>

// Problem constants (from reference):
//   x:   [B=32, C=128, H=32, W=32] float32  -> N = 32*32*32 = 32768 positions
//   emb: [K=512, D=128] float32
// Outputs concatenated in d_out (float32):
//   out0: quantized_st [B,C,H,W] = 4194304 floats  @ 0
//   out1: vq_loss scalar                            @ 4194304
//   out2: indices [B,H,W] = 32768 (as float)        @ 4194305
//   out3: usage scalar                              @ 4227073
//
// CORRECTNESS-CRITICAL NUMERICS: the np reference computes distances in f32 as
//   fl( fl(fsq_n + esq_k) - 2*dot_nk ),  fsq_n ~ 128  =>  distances quantized
// at ulp(128)=1.5e-5. ~2e-3 of positions have top-2 gap below 1 ulp, so the
// argmin is decided by rounding ties (lowest index wins). We must replicate
// numpy's exact f32 arithmetic: pairwise 8-accumulator sums for fsq/esq,
// sequential-k FMA chain for the dot (matching BLAS sgemm microkernels).

#define NPOS   32768
#define KCODES 512
#define DCH    128
#define NELEM  4194304   // 32*128*32*32

#define OFF_LOSS  4194304
#define OFF_IDX   4194305
#define OFF_USAGE 4227073

// Force a float to round to f32 storage (defeat -ffp-contract=fast fusion).
__device__ __forceinline__ float round_barrier(float v) {
    asm volatile("" : "+v"(v));
    return v;
}

// numpy pairwise_sum base case for n=128 contiguous floats of squares:
//   r[j] = sum of a[j], a[8+j], ..., a[120+j]  (sequential, ascending)
//   res  = ((r0+r1)+(r2+r3)) + ((r4+r5)+(r6+r7))
// where a[i] = fl(v_i * v_i) (elementwise square rounded BEFORE summation).

// ---------------- kernel: precompute ||e_k||^2 (numpy order) + zero flags ----------------
__global__ __launch_bounds__(512) void vq_prep(const float* __restrict__ emb,
                                               float* __restrict__ esq,
                                               int* __restrict__ flags) {
    int k = threadIdx.x;  // 0..511
    const float* row = emb + (size_t)k * DCH;
    float r[8];
#pragma unroll
    for (int j = 0; j < 8; ++j) {
        float v = row[j];
        r[j] = round_barrier(v * v);
    }
#pragma unroll
    for (int i = 8; i < DCH; i += 8) {
#pragma unroll
        for (int j = 0; j < 8; ++j) {
            float v = row[i + j];
            float sq = round_barrier(v * v);
            r[j] += sq;
        }
    }
    esq[k] = ((r[0] + r[1]) + (r[2] + r[3])) + ((r[4] + r[5]) + (r[6] + r[7]));
    flags[k] = 0;
}

// ---------------- kernel: fused distance GEMM + argmin ----------------
// 512 blocks, 256 threads. Each block: 64 consecutive positions vs all 512 codes.
__global__ __launch_bounds__(256) void vq_argmin(const float* __restrict__ x,
                                                 const float* __restrict__ emb,
                                                 const float* __restrict__ esq,
                                                 int* __restrict__ ws_idx,
                                                 int* __restrict__ flags,
                                                 float* __restrict__ out_idx) {
    __shared__ float xt[DCH][64];   // [c][p]  32 KB
    __shared__ float et[DCH][64];   // [c][kk] 32 KB
    __shared__ float red_d[16][64]; // [tx][p] 4 KB
    __shared__ int   red_i[16][64]; // 4 KB
    __shared__ float sfsq[64];      // numpy-order ||f||^2 per position

    const int t   = threadIdx.x;
    const int n0  = blockIdx.x * 64;       // first position of this block
    const int b   = n0 >> 10;              // batch (64 | 1024, never spans b)
    const int hw0 = n0 & 1023;

    // --- stage x tile: xt[c][p] = x[(b*128+c)*1024 + hw0 + p], float4 over p ---
    {
        const int cg = t >> 4;        // 0..15
        const int p4 = (t & 15) * 4;  // 0,4,...,60
#pragma unroll
        for (int it = 0; it < 8; ++it) {
            int c = it * 16 + cg;
            float4 v = *reinterpret_cast<const float4*>(
                x + (size_t)(b * DCH + c) * 1024 + hw0 + p4);
            *reinterpret_cast<float4*>(&xt[c][p4]) = v;
        }
    }
    __syncthreads();

    // --- fsq per position, numpy pairwise 8-accumulator order ---
    if (t < 64) {
        float r[8];
#pragma unroll
        for (int j = 0; j < 8; ++j) {
            float v = xt[j][t];
            r[j] = round_barrier(v * v);
        }
#pragma unroll
        for (int i = 8; i < DCH; i += 8) {
#pragma unroll
            for (int j = 0; j < 8; ++j) {
                float v = xt[i + j][t];
                float sq = round_barrier(v * v);
                r[j] += sq;
            }
        }
        sfsq[t] = ((r[0] + r[1]) + (r[2] + r[3])) + ((r[4] + r[5]) + (r[6] + r[7]));
    }
    __syncthreads();

    const int ty = t >> 4;   // 0..15  (position group)
    const int tx = t & 15;   // 0..15  (code group)

    float fsqr[4];
#pragma unroll
    for (int i = 0; i < 4; ++i) fsqr[i] = sfsq[ty * 4 + i];

    float best_d[4];
    int   best_i[4];
#pragma unroll
    for (int i = 0; i < 4; ++i) { best_d[i] = 3.4e38f; best_i[i] = 0; }

    for (int ch = 0; ch < 8; ++ch) {
        if (ch) __syncthreads();  // prev compute done before overwriting et

        // --- stage emb chunk (64 codes) transposed: et[c][kk] ---
        {
            const int kk = t >> 2;      // 0..63
            const int j  = t & 3;       // 0..3
            const float* row = emb + (size_t)(ch * 64 + kk) * DCH;
#pragma unroll
            for (int r = 0; r < 8; ++r) {
                int c0 = j * 32 + r * 4;
                float4 v = *reinterpret_cast<const float4*>(row + c0);
                et[c0 + 0][kk] = v.x;
                et[c0 + 1][kk] = v.y;
                et[c0 + 2][kk] = v.z;
                et[c0 + 3][kk] = v.w;
            }
        }
        __syncthreads();

        // --- 4x4 register-tile dot products, sequential-k single FMA chain ---
        float acc[4][4];
#pragma unroll
        for (int i = 0; i < 4; ++i)
#pragma unroll
            for (int j = 0; j < 4; ++j) acc[i][j] = 0.f;

#pragma unroll 4
        for (int c = 0; c < DCH; ++c) {
            float4 xv = *reinterpret_cast<const float4*>(&xt[c][ty * 4]);
            float4 ev = *reinterpret_cast<const float4*>(&et[c][tx * 4]);
            float xa[4] = {xv.x, xv.y, xv.z, xv.w};
            float ea[4] = {ev.x, ev.y, ev.z, ev.w};
#pragma unroll
            for (int i = 0; i < 4; ++i)
#pragma unroll
                for (int j = 0; j < 4; ++j)
                    acc[i][j] = __builtin_fmaf(xa[i], ea[j], acc[i][j]);
        }

        // --- fold chunk: s = fl( fl(fsq + esq) - 2*dot ), ref's rounding ---
#pragma unroll
        for (int j = 0; j < 4; ++j) {
            int kg = ch * 64 + tx * 4 + j;
            float eq = esq[kg];
#pragma unroll
            for (int i = 0; i < 4; ++i) {
                float A = fsqr[i] + eq;          // rounds once (ulp ~1.5e-5!)
                float s = A - 2.f * acc[i][j];   // 2*acc exact; rounds once
                if (s < best_d[i]) { best_d[i] = s; best_i[i] = kg; }
            }
        }
    }

    // --- cross-thread reduction over tx (16 threads per position) ---
#pragma unroll
    for (int i = 0; i < 4; ++i) {
        red_d[tx][ty * 4 + i] = best_d[i];
        red_i[tx][ty * 4 + i] = best_i[i];
    }
    __syncthreads();

    if (t < 64) {
        int p = t;
        float bd = red_d[0][p];
        int   bi = red_i[0][p];
#pragma unroll
        for (int q = 1; q < 16; ++q) {
            float d = red_d[q][p];
            int   i = red_i[q][p];
            if (d < bd || (d == bd && i < bi)) { bd = d; bi = i; }
        }
        int n = n0 + p;
        ws_idx[n]  = bi;
        out_idx[n] = (float)bi;
        flags[bi]  = 1;  // benign same-value race
    }
}

// ---------------- kernel: gather quantized, STE output, loss partials ----------------
__global__ __launch_bounds__(256) void vq_gather(const float* __restrict__ x,
                                                 const float* __restrict__ emb,
                                                 const int* __restrict__ ws_idx,
                                                 float* __restrict__ out0,
                                                 double* __restrict__ partials) {
    __shared__ double sd[256];
    const int t = threadIdx.x;
    double local = 0.0;
    // 2048 blocks * 256 threads * 8 iters = 4194304 elements exactly
    for (int e = blockIdx.x * 256 + t; e < NELEM; e += 2048 * 256) {
        int bc = e >> 10;          // b*128 + c
        int hw = e & 1023;
        int c  = bc & 127;
        int bb = bc >> 7;
        int n  = bb * 1024 + hw;
        int idx = ws_idx[n];
        float q  = emb[(size_t)idx * DCH + c];
        float xv = x[e];
        float dq = q - xv;          // matches ref's float32 (quantized - x)
        out0[e] = xv + dq;          // straight-through value, same rounding as ref
        local += (double)(dq * dq);
    }
    sd[t] = local;
    __syncthreads();
    for (int s = 128; s > 0; s >>= 1) {
        if (t < s) sd[t] += sd[t + s];
        __syncthreads();
    }
    if (t == 0) partials[blockIdx.x] = sd[0];
}

// ---------------- kernel: finalize loss + usage ----------------
__global__ __launch_bounds__(512) void vq_final(const double* __restrict__ partials,
                                                const int* __restrict__ flags,
                                                float* __restrict__ out_loss,
                                                float* __restrict__ out_usage) {
    __shared__ double sd[512];
    __shared__ int    si[512];
    const int t = threadIdx.x;
    double s = 0.0;
    for (int i = t; i < 2048; i += 512) s += partials[i];
    sd[t] = s;
    si[t] = flags[t];
    __syncthreads();
    for (int k = 256; k > 0; k >>= 1) {
        if (t < k) { sd[t] += sd[t + k]; si[t] += si[t + k]; }
        __syncthreads();
    }
    if (t == 0) {
        float m = (float)(sd[0] / (double)NELEM);
        *out_loss  = m + 0.25f * m;                 // q_loss + 0.25*e_loss
        *out_usage = (float)si[0] / (float)KCODES;  // used codes / K
    }
}

extern "C" void kernel_launch(void* const* d_in, const int* in_sizes, int n_in,
                              void* d_out, int out_size, void* d_ws, size_t ws_size,
                              hipStream_t stream) {
    const float* x   = (const float*)d_in[0];
    const float* emb = (const float*)d_in[1];
    float* out = (float*)d_out;

    float* out0      = out;
    float* out_loss  = out + OFF_LOSS;
    float* out_idx   = out + OFF_IDX;
    float* out_usage = out + OFF_USAGE;

    char* ws = (char*)d_ws;
    int*    ws_idx   = (int*)ws;
    int*    ws_flags = (int*)(ws + 131072);
    float*  ws_esq   = (float*)(ws + 133120);
    double* ws_part  = (double*)(ws + 135168);

    vq_prep  <<<1,    512, 0, stream>>>(emb, ws_esq, ws_flags);
    vq_argmin<<<512,  256, 0, stream>>>(x, emb, ws_esq, ws_idx, ws_flags, out_idx);
    vq_gather<<<2048, 256, 0, stream>>>(x, emb, ws_idx, out0, ws_part);
    vq_final <<<1,    512, 0, stream>>>(ws_part, ws_flags, out_loss, out_usage);
}

// Round 4
// 108.025 us; speedup vs baseline: 1.1748x; 1.1748x over previous
//
#include <hip/hip_runtime.h>
#include <hip/hip_bf16.h>

// x: [32,128,32,32] f32 -> N=32768 positions, D=128; emb: [512,128] f32.
// d_out: out0 quantized_st (4194304) | loss (1) | indices (32768) | usage (1)
//
// NUMERICS ARE CORRECTNESS-CRITICAL (verified passing in round 2):
//  - esq/fsq: numpy pairwise 8-accumulator pattern, squares rounded pre-sum
//  - dot: single sequential FMA chain over c = 0..127 ascending
//  - dist: s = fl( fl(fsq + esq) - 2*dot ), tie -> lowest index
//  - loss: dq f32; square f32; accumulate f64
// Do not change accumulation order in future rounds.

#define DCH    128
#define KCODES 512
#define NELEM  4194304
#define POSB   32          // positions per block
#define NBLK   1024        // 32768/32

#define OFF_LOSS  4194304
#define OFF_IDX   4194305
#define OFF_USAGE 4227073

// ws layout: flags 512*4 @0 | esq 512*4 @2048 | partials 1024*8 @4096

__device__ __forceinline__ float round_barrier(float v) {
    asm volatile("" : "+v"(v));
    return v;
}

// ---------------- prep: ||e_k||^2 (numpy order) + zero flags ----------------
__global__ __launch_bounds__(512) void vq_prep(const float* __restrict__ emb,
                                               float* __restrict__ esq,
                                               int* __restrict__ flags) {
    int k = threadIdx.x;
    const float* row = emb + (size_t)k * DCH;
    float r[8];
#pragma unroll
    for (int j = 0; j < 8; ++j) { float v = row[j]; r[j] = round_barrier(v * v); }
#pragma unroll
    for (int i = 8; i < DCH; i += 8) {
#pragma unroll
        for (int j = 0; j < 8; ++j) {
            float v = row[i + j];
            float sq = round_barrier(v * v);
            r[j] += sq;
        }
    }
    esq[k] = ((r[0] + r[1]) + (r[2] + r[3])) + ((r[4] + r[5]) + (r[6] + r[7]));
    flags[k] = 0;
}

// ---------------- main: distances + argmin + gather/STE + loss partials ----
// 1024 blocks x 256 threads. Block: 32 positions vs all 512 codes.
// ty = wave (4 pos groups of 8), tx = lane (64 code groups of 8). acc[8][8].
__global__ __launch_bounds__(256, 4) void vq_main(const float* __restrict__ x,
                                                  const float* __restrict__ emb,
                                                  const float* __restrict__ esq,
                                                  int* __restrict__ flags,
                                                  float* __restrict__ out0,
                                                  float* __restrict__ out_idx,
                                                  double* __restrict__ partials) {
    __shared__ __align__(16) float xt[16][32];      // 2 KB  (c-chunk x tile)
    __shared__ __align__(16) float et[16][512];     // 32 KB (c-chunk emb^T; reused for sr/sd)
    __shared__ float esq_s[KCODES];                 // 2 KB
    __shared__ float sfsq[POSB];
    __shared__ int   sbi[POSB];

    const int t   = threadIdx.x;
    const int n0  = blockIdx.x * POSB;
    const int b   = n0 >> 10;
    const int hw0 = n0 & 1023;
    const float* xb = x + (size_t)b * DCH * 1024 + hw0;

    // stage esq table
    esq_s[t]       = esq[t];
    esq_s[t + 256] = esq[t + 256];

    // fsq, numpy 8-accumulator: thread (p = t>>3, j = t&7) does r_j for pos p
    {
        const int p = t >> 3, j = t & 7;
        float r;
        {
            float v = xb[(size_t)j * 1024 + p];
            r = round_barrier(v * v);
        }
#pragma unroll
        for (int i = 1; i < 16; ++i) {
            float v = xb[(size_t)(8 * i + j) * 1024 + p];
            float sq = round_barrier(v * v);
            r += sq;
        }
        float (*sr)[POSB] = (float (*)[POSB]) & et[0][0];
        sr[j][p] = r;
    }
    __syncthreads();
    if (t < POSB) {
        float (*sr)[POSB] = (float (*)[POSB]) & et[0][0];
        sfsq[t] = ((sr[0][t] + sr[1][t]) + (sr[2][t] + sr[3][t]))
                + ((sr[4][t] + sr[5][t]) + (sr[6][t] + sr[7][t]));
    }

    const int ty = t >> 6;   // wave id = pos group
    const int tx = t & 63;   // lane    = code group

    float acc[8][8];
#pragma unroll
    for (int i = 0; i < 8; ++i)
#pragma unroll
        for (int j = 0; j < 8; ++j) acc[i][j] = 0.f;

    const int kst = t >> 2;   // staging: k lane base (coalesced emb reads)
    const int jst = t & 3;    // float4 slot within 16-c chunk

    for (int cc = 0; cc < 8; ++cc) {
        __syncthreads();  // prev compute done (and sr consumed at cc=0)

        // stage x chunk: xt[cl][p], cl = t>>4, p = (t&15)*2
        {
            const int cl = t >> 4;
            const int p2 = (t & 15) * 2;
            float2 v = *reinterpret_cast<const float2*>(
                xb + (size_t)(cc * 16 + cl) * 1024 + p2);
            *reinterpret_cast<float2*>(&xt[cl][p2]) = v;
        }
        // stage emb chunk transposed: et[cl][k] = emb[k][cc*16+cl]
#pragma unroll
        for (int r = 0; r < 8; ++r) {
            const int k = kst + 64 * r;
            float4 v = *reinterpret_cast<const float4*>(
                emb + (size_t)k * DCH + cc * 16 + jst * 4);
            et[jst * 4 + 0][k] = v.x;
            et[jst * 4 + 1][k] = v.y;
            et[jst * 4 + 2][k] = v.z;
            et[jst * 4 + 3][k] = v.w;
        }
        __syncthreads();

        // 8x8 register tile; x reads are wave-uniform broadcasts
#pragma unroll
        for (int cl = 0; cl < 16; ++cl) {
            float4 xv0 = *reinterpret_cast<const float4*>(&xt[cl][ty * 8]);
            float4 xv1 = *reinterpret_cast<const float4*>(&xt[cl][ty * 8 + 4]);
            float4 ev0 = *reinterpret_cast<const float4*>(&et[cl][tx * 8]);
            float4 ev1 = *reinterpret_cast<const float4*>(&et[cl][tx * 8 + 4]);
            float xa[8] = {xv0.x, xv0.y, xv0.z, xv0.w, xv1.x, xv1.y, xv1.z, xv1.w};
            float ea[8] = {ev0.x, ev0.y, ev0.z, ev0.w, ev1.x, ev1.y, ev1.z, ev1.w};
#pragma unroll
            for (int i = 0; i < 8; ++i)
#pragma unroll
                for (int j = 0; j < 8; ++j)
                    acc[i][j] = __builtin_fmaf(xa[i], ea[j], acc[i][j]);
        }
    }

    // fold distances + per-thread argmin (ascending j -> lowest-index ties)
    float bd[8];
    int   bi[8];
#pragma unroll
    for (int i = 0; i < 8; ++i) { bd[i] = 3.4e38f; bi[i] = 0; }
#pragma unroll
    for (int j = 0; j < 8; ++j) {
        const int kg = tx * 8 + j;
        const float eq = esq_s[kg];
#pragma unroll
        for (int i = 0; i < 8; ++i) {
            float A = sfsq[ty * 8 + i] + eq;   // rounds once (ulp ~1.5e-5)
            float s = A - 2.f * acc[i][j];     // 2*acc exact; rounds once
            if (s < bd[i]) { bd[i] = s; bi[i] = kg; }
        }
    }
    // 64-lane butterfly reduce, lexicographic (d, idx)
#pragma unroll
    for (int m = 1; m < 64; m <<= 1) {
#pragma unroll
        for (int i = 0; i < 8; ++i) {
            float d2 = __shfl_xor(bd[i], m, 64);
            int   i2 = __shfl_xor(bi[i], m, 64);
            if (d2 < bd[i] || (d2 == bd[i] && i2 < bi[i])) { bd[i] = d2; bi[i] = i2; }
        }
    }
    if (tx == 0) {
#pragma unroll
        for (int i = 0; i < 8; ++i) {
            const int p = ty * 8 + i;
            out_idx[n0 + p] = (float)bi[i];
            sbi[p] = bi[i];
            flags[bi[i]] = 1;   // benign same-value race
        }
    }
    __syncthreads();

    // fused gather + straight-through write + f64 loss partial
    double local = 0.0;
    {
        const int cl8 = t >> 3;          // 0..31 (c row base)
        const int p4  = (t & 7) * 4;     // 0..28
        const int i0 = sbi[p4], i1 = sbi[p4 + 1], i2 = sbi[p4 + 2], i3 = sbi[p4 + 3];
#pragma unroll
        for (int it = 0; it < 4; ++it) {
            const int c = it * 32 + cl8;
            float4 xv = *reinterpret_cast<const float4*>(xb + (size_t)c * 1024 + p4);
            float q0 = emb[(size_t)i0 * DCH + c];
            float q1 = emb[(size_t)i1 * DCH + c];
            float q2 = emb[(size_t)i2 * DCH + c];
            float q3 = emb[(size_t)i3 * DCH + c];
            float d0 = q0 - xv.x, d1 = q1 - xv.y, d2 = q2 - xv.z, d3 = q3 - xv.w;
            float4 o = {xv.x + d0, xv.y + d1, xv.z + d2, xv.w + d3};
            *reinterpret_cast<float4*>(
                out0 + (size_t)(b * DCH + c) * 1024 + hw0 + p4) = o;
            local += (double)(d0 * d0);
            local += (double)(d1 * d1);
            local += (double)(d2 * d2);
            local += (double)(d3 * d3);
        }
    }
    // block f64 reduce (reuse et)
    double* sd = reinterpret_cast<double*>(&et[0][0]);
    sd[t] = local;
    __syncthreads();
    for (int s = 128; s > 0; s >>= 1) {
        if (t < s) sd[t] += sd[t + s];
        __syncthreads();
    }
    if (t == 0) partials[blockIdx.x] = sd[0];
}

// ---------------- finalize: loss + usage ----------------
__global__ __launch_bounds__(512) void vq_final(const double* __restrict__ partials,
                                                const int* __restrict__ flags,
                                                float* __restrict__ out_loss,
                                                float* __restrict__ out_usage) {
    __shared__ double sd[512];
    __shared__ int    si[512];
    const int t = threadIdx.x;
    double s = partials[t] + partials[t + 512];
    sd[t] = s;
    si[t] = flags[t];
    __syncthreads();
    for (int k = 256; k > 0; k >>= 1) {
        if (t < k) { sd[t] += sd[t + k]; si[t] += si[t + k]; }
        __syncthreads();
    }
    if (t == 0) {
        float m = (float)(sd[0] / (double)NELEM);
        *out_loss  = m + 0.25f * m;
        *out_usage = (float)si[0] / (float)KCODES;
    }
}

extern "C" void kernel_launch(void* const* d_in, const int* in_sizes, int n_in,
                              void* d_out, int out_size, void* d_ws, size_t ws_size,
                              hipStream_t stream) {
    const float* x   = (const float*)d_in[0];
    const float* emb = (const float*)d_in[1];
    float* out = (float*)d_out;

    float* out0      = out;
    float* out_loss  = out + OFF_LOSS;
    float* out_idx   = out + OFF_IDX;
    float* out_usage = out + OFF_USAGE;

    char* ws = (char*)d_ws;
    int*    ws_flags = (int*)ws;
    float*  ws_esq   = (float*)(ws + 2048);
    double* ws_part  = (double*)(ws + 4096);

    vq_prep <<<1,    512, 0, stream>>>(emb, ws_esq, ws_flags);
    vq_main <<<NBLK, 256, 0, stream>>>(x, emb, ws_esq, ws_flags, out0, out_idx, ws_part);
    vq_final<<<1,    512, 0, stream>>>(ws_part, ws_flags, out_loss, out_usage);
}